// Round 1
// baseline (114.598 us; speedup 1.0000x reference)
//
#include <hip/hip_runtime.h>
#include <hip/hip_bf16.h>
#include <cstdint>

typedef unsigned short u16;
typedef __attribute__((ext_vector_type(8))) short short8;   // 8 bf16 = 4 VGPR
typedef __attribute__((ext_vector_type(4))) float f32x4;

#define MFMA16(a, b, c) __builtin_amdgcn_mfma_f32_16x16x32_bf16((a), (b), (c), 0, 0, 0)

constexpr int Bn   = 16;
constexpr int Tn   = 2048;
constexpr int Cn   = 384;
constexpr int Hn   = 64;
constexpr int XPAD = 392;  // x LDS row stride (bf16 elems): 384+8, keeps 16B align, breaks bank pow2
constexpr int WPAD = 72;   // 64+8

// f32 -> bf16 round-to-nearest-even
__device__ __forceinline__ u16 f2bf(float f) {
  union { float f; uint32_t u; } c; c.f = f;
  uint32_t u = c.u;
  return (u16)((u + 0x7fffu + ((u >> 16) & 1u)) >> 16);
}

// ---------------------------------------------------------------------------
// Kernel 1: fused QKV projection.  x[32768,384] f32 @ W[384,64] + b  -> bf16
// Q is pre-scaled by 1/sqrt(64) so the attention kernel skips the scale.
// Grid: 512 blocks x 256 thr; each block computes 64 rows of all 3 outputs.
// ---------------------------------------------------------------------------
__global__ __launch_bounds__(256) void qkv_proj(
    const float* __restrict__ x,
    const float* __restrict__ Wq, const float* __restrict__ bq,
    const float* __restrict__ Wk, const float* __restrict__ bk,
    const float* __restrict__ Wv, const float* __restrict__ bv,
    u16* __restrict__ oq, u16* __restrict__ ok, u16* __restrict__ ov)
{
  __shared__ u16 xs[64 * XPAD];       // x tile, bf16, row-major
  __shared__ u16 wt[Hn * WPAD];       // W chunk, TRANSPOSED [h][k]

  const int t    = threadIdx.x;
  const int lane = t & 63;
  const int w    = t >> 6;            // wave 0..3, owns rows w*16..w*16+15
  const int l15  = lane & 15;
  const int lh   = lane >> 4;
  const long r0  = (long)blockIdx.x * 64;

  // ---- stage x tile (f32 -> bf16), coalesced float4 reads ----
  #pragma unroll
  for (int i = 0; i < 24; ++i) {
    int f4  = t + i * 256;            // 6144 float4s total
    int row = f4 / 96, col4 = f4 % 96;
    const float4 xv = *reinterpret_cast<const float4*>(x + (r0 + row) * Cn + col4 * 4);
    u16 h0 = f2bf(xv.x), h1 = f2bf(xv.y), h2 = f2bf(xv.z), h3 = f2bf(xv.w);
    u16* p = &xs[row * XPAD + col4 * 4];
    p[0] = h0; p[1] = h1; p[2] = h2; p[3] = h3;
  }

  const float* Ws[3] = {Wq, Wk, Wv};
  const float* bs[3] = {bq, bk, bv};
  u16*         os[3] = {oq, ok, ov};

  for (int m = 0; m < 3; ++m) {
    const float* __restrict__ W = Ws[m];
    f32x4 acc[4];
    #pragma unroll
    for (int n = 0; n < 4; ++n) acc[n] = f32x4{0.f, 0.f, 0.f, 0.f};

    for (int kc = 0; kc < 6; ++kc) {      // K chunks of 64
      __syncthreads();                    // wt free to overwrite (also covers xs on first pass)
      {
        // stage W[kc*64 .. +63][0..63] transposed into wt[h][kk]
        int kk = t >> 2;
        int h0 = (t & 3) * 16;
        const float* wrow = W + (size_t)(kc * 64 + kk) * Hn + h0;
        #pragma unroll
        for (int j = 0; j < 16; ++j)
          wt[(h0 + j) * WPAD + kk] = f2bf(wrow[j]);
      }
      __syncthreads();

      #pragma unroll
      for (int ks = 0; ks < 2; ++ks) {
        const short8 a = *reinterpret_cast<const short8*>(
            &xs[(w * 16 + l15) * XPAD + kc * 64 + ks * 32 + lh * 8]);
        #pragma unroll
        for (int n = 0; n < 4; ++n) {
          const short8 b = *reinterpret_cast<const short8*>(
              &wt[(n * 16 + l15) * WPAD + ks * 32 + lh * 8]);
          acc[n] = MFMA16(a, b, acc[n]);
        }
      }
    }

    // epilogue: + bias, (Q only) * 1/8, -> bf16
    const float* bias = bs[m];
    u16*         dst  = os[m];
    const float  scl  = (m == 0) ? 0.125f : 1.0f;
    #pragma unroll
    for (int n = 0; n < 4; ++n) {
      int col = n * 16 + l15;
      float bb = bias[col];
      #pragma unroll
      for (int r = 0; r < 4; ++r) {
        int row = lh * 4 + r;                       // D-frag: row=(lane>>4)*4+reg, col=lane&15
        float val = (acc[n][r] + bb) * scl;
        dst[(r0 + w * 16 + row) * Hn + col] = f2bf(val);
      }
    }
  }
}

// ---------------------------------------------------------------------------
// Kernel 2: flash attention, NO causal mask.
// Grid: 512 blocks (16 batches x 32 q-tiles of 64 rows), 256 thr = 4 waves.
// Each wave owns 16 q-rows; loop over 32 KV tiles of 64 keys.
// ---------------------------------------------------------------------------
__global__ __launch_bounds__(256) void flash_attn(
    const u16* __restrict__ q, const u16* __restrict__ k,
    const u16* __restrict__ v, float* __restrict__ out)
{
  constexpr int PD = 72;
  __shared__ u16 ksh[64 * PD];        // K tile row-major [kv][h]
  __shared__ u16 vts[Hn * PD];        // V tile TRANSPOSED [h][kv]
  __shared__ u16 ps[4][16 * PD];      // per-wave P tile [qrow][kv]

  const int t    = threadIdx.x;
  const int lane = t & 63;
  const int w    = t >> 6;
  const int l15  = lane & 15;
  const int lh   = lane >> 4;
  const int b    = blockIdx.x >> 5;
  const int qt   = blockIdx.x & 31;
  const long rowbase = (long)b * Tn + qt * 64;
  const long kvbase  = (long)b * Tn;

  // Q fragments: direct from global (contiguous 16B per lane), loop-invariant
  short8 aq[2];
  {
    const u16* qrow = q + (rowbase + w * 16 + l15) * Hn;
    aq[0] = *reinterpret_cast<const short8*>(qrow + lh * 8);
    aq[1] = *reinterpret_cast<const short8*>(qrow + 32 + lh * 8);
  }

  f32x4 o[4];
  #pragma unroll
  for (int n = 0; n < 4; ++n) o[n] = f32x4{0.f, 0.f, 0.f, 0.f};
  float mrun[4] = {-1e30f, -1e30f, -1e30f, -1e30f};
  float lrun[4] = {0.f, 0.f, 0.f, 0.f};

  const int sr = t >> 2;              // staging row 0..63
  const int sc = (t & 3) * 16;        // staging col group

  for (int it = 0; it < Tn / 64; ++it) {
    const long kv0 = kvbase + it * 64;
    {
      // stage K row-major (vector writes)
      const u16* src = k + (kv0 + sr) * Hn + sc;
      *reinterpret_cast<short8*>(&ksh[sr * PD + sc])     = *reinterpret_cast<const short8*>(src);
      *reinterpret_cast<short8*>(&ksh[sr * PD + sc + 8]) = *reinterpret_cast<const short8*>(src + 8);
      // stage V transposed (scalar writes, static indices)
      const u16* vsrc = v + (kv0 + sr) * Hn + sc;
      union { short8 s; u16 u[8]; } v0, v1;
      v0.s = *reinterpret_cast<const short8*>(vsrc);
      v1.s = *reinterpret_cast<const short8*>(vsrc + 8);
      #pragma unroll
      for (int j = 0; j < 8; ++j) vts[(sc + j) * PD + sr]     = v0.u[j];
      #pragma unroll
      for (int j = 0; j < 8; ++j) vts[(sc + 8 + j) * PD + sr] = v1.u[j];
    }
    __syncthreads();

    // S = Q K^T  (scale pre-folded into Q)
    f32x4 s[4];
    #pragma unroll
    for (int n = 0; n < 4; ++n) s[n] = f32x4{0.f, 0.f, 0.f, 0.f};
    #pragma unroll
    for (int ks = 0; ks < 2; ++ks) {
      #pragma unroll
      for (int n = 0; n < 4; ++n) {
        const short8 bk_ = *reinterpret_cast<const short8*>(
            &ksh[(n * 16 + l15) * PD + ks * 32 + lh * 8]);
        s[n] = MFMA16(aq[ks], bk_, s[n]);
      }
    }

    // ---- online softmax (rows live in 16-lane groups) ----
    float mblk[4];
    #pragma unroll
    for (int r = 0; r < 4; ++r)
      mblk[r] = fmaxf(fmaxf(s[0][r], s[1][r]), fmaxf(s[2][r], s[3][r]));
    #pragma unroll
    for (int off = 1; off < 16; off <<= 1) {
      #pragma unroll
      for (int r = 0; r < 4; ++r)
        mblk[r] = fmaxf(mblk[r], __shfl_xor(mblk[r], off));
    }
    float alpha[4], lsum[4];
    #pragma unroll
    for (int r = 0; r < 4; ++r) {
      float mnew = fmaxf(mrun[r], mblk[r]);
      alpha[r]   = __expf(mrun[r] - mnew);
      mrun[r]    = mnew;
      lsum[r]    = 0.f;
    }
    #pragma unroll
    for (int n = 0; n < 4; ++n) {
      #pragma unroll
      for (int r = 0; r < 4; ++r) {
        float p = __expf(s[n][r] - mrun[r]);
        s[n][r] = p;
        lsum[r] += p;
      }
    }
    #pragma unroll
    for (int off = 1; off < 16; off <<= 1) {
      #pragma unroll
      for (int r = 0; r < 4; ++r)
        lsum[r] += __shfl_xor(lsum[r], off);
    }
    #pragma unroll
    for (int r = 0; r < 4; ++r)
      lrun[r] = lrun[r] * alpha[r] + lsum[r];
    #pragma unroll
    for (int n = 0; n < 4; ++n) {
      #pragma unroll
      for (int r = 0; r < 4; ++r)
        o[n][r] *= alpha[r];
    }

    // ---- P -> LDS (re-shape D-frag layout into A-operand layout) ----
    u16* pw = &ps[w][0];
    #pragma unroll
    for (int n = 0; n < 4; ++n) {
      #pragma unroll
      for (int r = 0; r < 4; ++r)
        pw[(lh * 4 + r) * PD + n * 16 + l15] = f2bf(s[n][r]);
    }

    // ---- O += P V ----
    #pragma unroll
    for (int ks = 0; ks < 2; ++ks) {
      const short8 ap = *reinterpret_cast<const short8*>(
          &pw[l15 * PD + ks * 32 + lh * 8]);
      #pragma unroll
      for (int n = 0; n < 4; ++n) {
        const short8 bv_ = *reinterpret_cast<const short8*>(
            &vts[(n * 16 + l15) * PD + ks * 32 + lh * 8]);
        o[n] = MFMA16(ap, bv_, o[n]);
      }
    }
    __syncthreads();   // K/V tile free to overwrite
  }

  // epilogue: normalize and store f32
  #pragma unroll
  for (int n = 0; n < 4; ++n) {
    int col = n * 16 + l15;
    #pragma unroll
    for (int r = 0; r < 4; ++r) {
      int row = lh * 4 + r;
      out[(rowbase + w * 16 + row) * Hn + col] = o[n][r] / lrun[r];
    }
  }
}

// ---------------------------------------------------------------------------
extern "C" void kernel_launch(void* const* d_in, const int* in_sizes, int n_in,
                              void* d_out, int out_size, void* d_ws, size_t ws_size,
                              hipStream_t stream) {
  const float* x  = (const float*)d_in[0];
  const float* Wq = (const float*)d_in[1];
  const float* bq = (const float*)d_in[2];
  const float* Wk = (const float*)d_in[3];
  const float* bk = (const float*)d_in[4];
  const float* Wv = (const float*)d_in[5];
  const float* bv = (const float*)d_in[6];
  float* out = (float*)d_out;

  u16* qs = (u16*)d_ws;                          // [32768][64] bf16, pre-scaled by 1/8
  u16* ks = qs + (size_t)Bn * Tn * Hn;           // [32768][64] bf16
  u16* vs = ks + (size_t)Bn * Tn * Hn;           // [32768][64] bf16

  hipLaunchKernelGGL(qkv_proj, dim3((Bn * Tn) / 64), dim3(256), 0, stream,
                     x, Wq, bq, Wk, bk, Wv, bv, qs, ks, vs);
  hipLaunchKernelGGL(flash_attn, dim3((Bn * Tn) / 64), dim3(256), 0, stream,
                     qs, ks, vs, out);
}